// Round 2
// 1895.631 us; speedup vs baseline: 1.2419x; 1.2419x over previous
//
#include <hip/hip_runtime.h>
#include <hip/hip_bf16.h>

// Problem constants
#define BT    131072          // B*T = 32*4096
#define DD    96              // codebook dim
#define KCB   384             // codes per codebook
#define NCB   6               // codebooks
#define PROJ  192
#define W2V   768

// d_out layout (float32, concat in return order)
#define ZQT_OFF   0L
#define CODES_OFF 12582912L   // BT*DD
#define VQ_OFF    13369344L   // + BT*NCB
#define SEM_OFF   13369345L

// ws layout (bytes) — total ~340 KB (keep small: ws_size may be modest and
// overflowing d_ws corrupted adjacent allocations in R3)
#define ACC_OFF   0L          // 8 doubles: vq[0..5], sem[6]
#define E32_OFF   64L         // 2304 floats (np-pairwise fp32 ||e||^2)
#define W1T_OFF   9280L       // 192x96 bf16
#define W2T_OFF   46144L      // 768x192 bf16  (end: 341056)

// kq2 tiling: 4 tokens/thread share each LDS e-read; 4 waves split the 384
// codes (96 each, ascending -> tie-break preserved); 24-code accumulator tile
// amortizes the residual re-reads (residual lives in the ZQT output region as
// blocked-transposed scratch rg[kt][token] float4 — kr overwrites it later).
#define TT 4
#define CT 24
#define TB 256

typedef __attribute__((ext_vector_type(8))) short  bf16x8;
typedef __attribute__((ext_vector_type(4))) float  f32x4;

static __device__ __forceinline__ unsigned short f2bf(float x) {
    __hip_bfloat16 h = __float2bfloat16(x);
    return *reinterpret_cast<unsigned short*>(&h);
}
static __device__ __forceinline__ float comp(const float4& v, int c) {
    return c == 0 ? v.x : c == 1 ? v.y : c == 2 ? v.z : v.w;
}

// numpy pairwise_sum for n=96 (<=128 block): 8 strided accumulators over
// ascending blocks of 8, then tree combine ((r0+r1)+(r2+r3))+((r4+r5)+(r6+r7)).
static __device__ __forceinline__ float pairwise96_sq(const float4* r) {
    float a[8];
#pragma unroll
    for (int j = 0; j < 8; ++j) {
        const int c = j & 3, base = j >> 2;
        float x0 = comp(r[base], c);
        float s  = __fmul_rn(x0, x0);
#pragma unroll
        for (int t = 1; t < 12; ++t) {
            float x = comp(r[base + 2 * t], c);
            s = __fadd_rn(s, __fmul_rn(x, x));
        }
        a[j] = s;
    }
    return __fadd_rn(__fadd_rn(__fadd_rn(a[0], a[1]), __fadd_rn(a[2], a[3])),
                     __fadd_rn(__fadd_rn(a[4], a[5]), __fadd_rn(a[6], a[7])));
}

// ---------------------------------------------------------------- zero accums
__global__ void kzero(double* __restrict__ acc) {
    if (threadIdx.x < 8) acc[threadIdx.x] = 0.0;
}

// ------------------- fp32 codebook self-norms, numpy-pairwise order (n=96)
__global__ void kee(const float* __restrict__ cb, float* __restrict__ E32) {
    int c = blockIdx.x * 256 + threadIdx.x;
    if (c < NCB * KCB) {
        const float* row = cb + (size_t)c * DD;
        float a[8];
#pragma unroll
        for (int j = 0; j < 8; ++j) a[j] = __fmul_rn(row[j], row[j]);
        for (int t = 1; t < 12; ++t) {
#pragma unroll
            for (int j = 0; j < 8; ++j) {
                float x = row[8 * t + j];
                a[j] = __fadd_rn(a[j], __fmul_rn(x, x));
            }
        }
        E32[c] = __fadd_rn(__fadd_rn(__fadd_rn(a[0], a[1]), __fadd_rn(a[2], a[3])),
                           __fadd_rn(__fadd_rn(a[4], a[5]), __fadd_rn(a[6], a[7])));
    }
}

// ------------------------------------- transpose + bf16-cast w1, w2 for MFMA
__global__ void kwt(const float* __restrict__ w1, const float* __restrict__ w2,
                    __hip_bfloat16* __restrict__ w1T, __hip_bfloat16* __restrict__ w2T) {
    int i = blockIdx.x * 256 + threadIdx.x;
    if (i < DD * PROJ) {                  // w1 (96x192) -> w1T (192x96)
        int n = i / DD, k = i % DD;
        w1T[i] = __float2bfloat16(w1[k * PROJ + n]);
    }
    int j = i - DD * PROJ;
    if (j >= 0 && j < PROJ * W2V) {       // w2 (192x768) -> w2T (768x192)
        int n = j / PROJ, k = j % PROJ;
        w2T[j] = __float2bfloat16(w2[k * W2V + n]);
    }
}

// --------------------------------------------------------- Kernel Q2: argmin
// Bit-exact replication of the np gold (same chains as the validated R3 kq):
//   dist_k = fl32( fl32(S - C2_k) + E_k )
//   S  = numpy pairwise-8 sum of fl32(r_i^2)
//   C2 = sequential ascending-k FMA dot; here fma(2r, e) == fma(r, 2e) bitwise
//        (identical exact product inside the single FMA rounding)
//   argmin = first index of min (strict <). Wave w owns codes [96w,96w+96);
//   strict-< combine in ascending wave order == global ascending scan.
// Structure: TB=256 tokens/block, 4 waves code-split, TT=4 tokens/thread,
// CT=24-code accumulator tiles; residual in global scratch rg[kt][tok] float4
// (= ZQT region, overwritten later by kr); e staged wave-locally in LDS so
// each broadcast b128 feeds 16 FMAs (2x the old kernel's 8).
// NOTE: s/ct/kt loops are unroll-1 (code size + compile time); the c/j
// accumulator loops MUST stay fully unrolled (runtime-indexed ext-vector
// arrays go to scratch).
__global__ __launch_bounds__(256, 2) void kq2(
        const float* __restrict__ z, const float* __restrict__ cb,
        const float* __restrict__ E32, float* __restrict__ dout,
        float4* __restrict__ rg) {
    __shared__ __align__(16) float  e_lds[4][CT * DD];   // 36 KB, wave-local
    __shared__ __align__(16) float2 comb[4][TB];         // 8 KB  argmin combine
    __shared__ __align__(16) float  S_lds[TB];           // 1 KB  per-token ||r||^2

    const int tid = threadIdx.x, lane = tid & 63, w = tid >> 6;
    const long tok0 = (long)blockIdx.x * TB;

    // ---- phase 0: stage z -> rg (blocked-transposed) + initial S
    {
        const long t = tok0 + tid;
        const float4* z4 = (const float4*)(z + t * DD);
        float4 r[24];
#pragma unroll
        for (int i = 0; i < 24; ++i) r[i] = z4[i];
        S_lds[tid] = pairwise96_sq(r);
#pragma unroll
        for (int i = 0; i < 24; ++i) rg[(long)i * BT + t] = r[i];
    }
    __syncthreads();

#pragma unroll 1
    for (int s = 0; s < NCB; ++s) {
        // ---------------- dist phase: wave-local 96 codes, 4 tiles of CT
        float Sj[TT];
#pragma unroll
        for (int j = 0; j < TT; ++j) Sj[j] = S_lds[64 * j + lane];
        float mv[TT]; int bi[TT];
#pragma unroll
        for (int j = 0; j < TT; ++j) { mv[j] = 3.4e38f; bi[j] = 0; }

#pragma unroll 1
        for (int ct = 0; ct < 96 / CT; ++ct) {
            const int cbase = w * 96 + ct * CT;
            // stage this wave's 24-code e tile (9216 B, coalesced, wave-local;
            // same-wave ds_write->ds_read ordered by compiler lgkmcnt)
            {
                const float4* esrc = (const float4*)(cb + ((size_t)s * KCB + cbase) * DD);
                float4* edst = (float4*)&e_lds[w][0];
#pragma unroll
                for (int i = 0; i < 9; ++i) edst[i * 64 + lane] = esrc[i * 64 + lane];
            }
            float acc[CT][TT];
#pragma unroll
            for (int c = 0; c < CT; ++c)
#pragma unroll
                for (int j = 0; j < TT; ++j) acc[c][j] = 0.f;

            // k-ascending FMA chains, accumulator-resident across k-tiles
            float4 rv[TT];
#pragma unroll
            for (int j = 0; j < TT; ++j) rv[j] = rg[tok0 + 64 * j + lane];
#pragma unroll 1
            for (int kt = 0; kt < 24; ++kt) {
                float4 rnx[TT];
                if (kt < 23) {
#pragma unroll
                    for (int j = 0; j < TT; ++j)
                        rnx[j] = rg[(long)(kt + 1) * BT + tok0 + 64 * j + lane];
                }
                float4 r2[TT];
#pragma unroll
                for (int j = 0; j < TT; ++j) {
                    r2[j].x = __fmul_rn(2.f, rv[j].x); r2[j].y = __fmul_rn(2.f, rv[j].y);
                    r2[j].z = __fmul_rn(2.f, rv[j].z); r2[j].w = __fmul_rn(2.f, rv[j].w);
                }
                const float* eb = &e_lds[w][kt * 4];
#pragma unroll
                for (int c = 0; c < CT; ++c) {
                    float4 e = *(const float4*)(eb + c * DD);
#pragma unroll
                    for (int j = 0; j < TT; ++j) {
                        acc[c][j] = fmaf(r2[j].x, e.x, acc[c][j]);
                        acc[c][j] = fmaf(r2[j].y, e.y, acc[c][j]);
                        acc[c][j] = fmaf(r2[j].z, e.z, acc[c][j]);
                        acc[c][j] = fmaf(r2[j].w, e.w, acc[c][j]);
                    }
                }
#pragma unroll
                for (int j = 0; j < TT; ++j) rv[j] = rnx[j];
            }
#pragma unroll
            for (int c = 0; c < CT; ++c) {
                const float E = E32[s * KCB + cbase + c];
#pragma unroll
                for (int j = 0; j < TT; ++j) {
                    float d = __fadd_rn(__fsub_rn(Sj[j], acc[c][j]), E);
                    if (d < mv[j]) { mv[j] = d; bi[j] = cbase + c; }
                }
            }
        }
#pragma unroll
        for (int j = 0; j < TT; ++j)
            comb[w][64 * j + lane] = make_float2(mv[j], (float)bi[j]);
        __syncthreads();

        // ---------------- combine + straight-through residual update
        {
            const long t = tok0 + tid;
            float bv = comb[0][tid].x; int bidx = (int)comb[0][tid].y;
#pragma unroll
            for (int w2 = 1; w2 < 4; ++w2) {
                float2 cnd = comb[w2][tid];
                if (cnd.x < bv) { bv = cnd.x; bidx = (int)cnd.y; }
            }
            dout[CODES_OFF + t * NCB + s] = (float)bidx;
            if (s < NCB - 1) {
                const float4* q4 = (const float4*)(cb + ((size_t)s * KCB + bidx) * DD);
                float4 rn[24];
#pragma unroll
                for (int i = 0; i < 24; ++i) {
                    float4 rv = rg[(long)i * BT + t], q = q4[i];
                    float4 d, st;
                    d.x = __fsub_rn(q.x, rv.x); d.y = __fsub_rn(q.y, rv.y);
                    d.z = __fsub_rn(q.z, rv.z); d.w = __fsub_rn(q.w, rv.w);
                    st.x = __fadd_rn(rv.x, d.x); st.y = __fadd_rn(rv.y, d.y);
                    st.z = __fadd_rn(rv.z, d.z); st.w = __fadd_rn(rv.w, d.w);
                    rn[i].x = __fsub_rn(rv.x, st.x); rn[i].y = __fsub_rn(rv.y, st.y);
                    rn[i].z = __fsub_rn(rv.z, st.z); rn[i].w = __fsub_rn(rv.w, st.w);
                }
                S_lds[tid] = pairwise96_sq(rn);
#pragma unroll
                for (int i = 0; i < 24; ++i) rg[(long)i * BT + t] = rn[i];
            }
        }
        __syncthreads();
    }
}

// ------------------------------------------- Kernel R: replay from codes
// Identical fp32 elementwise chain -> z_q_total; fp64 vq sums.
__global__ __launch_bounds__(256) void kr(
        const float* __restrict__ z, const float* __restrict__ cb,
        const float* __restrict__ codesf, float* __restrict__ zqt_out,
        double* __restrict__ acc) {
    const long tok = (long)blockIdx.x * 256 + threadIdx.x;
    float4 r[24], zqt[24];
    const float4* z4 = (const float4*)(z + tok * DD);
#pragma unroll
    for (int i = 0; i < 24; ++i) r[i] = z4[i];
    double ls[NCB];
#pragma unroll
    for (int s = 0; s < NCB; ++s) {
        const int idx = (int)codesf[tok * NCB + s];
        const float4* q4 = (const float4*)(cb + (size_t)(s * KCB + idx) * DD);
        double a = 0.0;
#pragma unroll
        for (int i = 0; i < 24; ++i) {
            float4 q = q4[i];
            float4 d, st;
            d.x = __fsub_rn(q.x, r[i].x); d.y = __fsub_rn(q.y, r[i].y);
            d.z = __fsub_rn(q.z, r[i].z); d.w = __fsub_rn(q.w, r[i].w);
            st.x = __fadd_rn(r[i].x, d.x); st.y = __fadd_rn(r[i].y, d.y);
            st.z = __fadd_rn(r[i].z, d.z); st.w = __fadd_rn(r[i].w, d.w);
            if (s == 0) {
                zqt[i] = st;
            } else {
                zqt[i].x = __fadd_rn(zqt[i].x, st.x); zqt[i].y = __fadd_rn(zqt[i].y, st.y);
                zqt[i].z = __fadd_rn(zqt[i].z, st.z); zqt[i].w = __fadd_rn(zqt[i].w, st.w);
            }
            r[i].x = __fsub_rn(r[i].x, st.x); r[i].y = __fsub_rn(r[i].y, st.y);
            r[i].z = __fsub_rn(r[i].z, st.z); r[i].w = __fsub_rn(r[i].w, st.w);
            a += (double)d.x * (double)d.x; a += (double)d.y * (double)d.y;
            a += (double)d.z * (double)d.z; a += (double)d.w * (double)d.w;
        }
        ls[s] = a;
    }
    float4* o4 = (float4*)(zqt_out + tok * DD);
#pragma unroll
    for (int i = 0; i < 24; ++i) o4[i] = zqt[i];
#pragma unroll
    for (int s = 0; s < NCB; ++s) {
        double v = ls[s];
        for (int off = 32; off > 0; off >>= 1) v += __shfl_down(v, off, 64);
        if ((threadIdx.x & 63) == 0) atomicAdd(&acc[s], v);
    }
}

// --------------------------- Kernel H: fused semantic head (bf16 MFMA)
// Recomputes stage-0 straight-through values from z + cb + codes (identical
// fp32 op sequence as kr/kq2: st = r + (q - r)), builds A-fragments directly.
__global__ __launch_bounds__(256) void kh(
        const float* __restrict__ z, const float* __restrict__ cb,
        const float* __restrict__ codesf,
        const __hip_bfloat16* __restrict__ w1T, const float* __restrict__ b1,
        const __hip_bfloat16* __restrict__ w2T, const float* __restrict__ b2,
        const float* __restrict__ tgt, double* __restrict__ sem_acc) {
    __shared__ unsigned short hs[64][PROJ + 8];   // +8 pad: conflict-free b128
    const int lane = threadIdx.x & 63, wv = threadIdx.x >> 6;
    const int col  = lane & 15, quad = lane >> 4;
    const long m0  = (long)blockIdx.x * 64 + wv * 16;

    // phase 1 A-fragments: this lane's row = token m0+col, k = ks*32+quad*8..+8
    const long tokrow = m0 + col;
    const int  code0  = (int)codesf[tokrow * NCB];
    const float* zr = z  + tokrow * DD;
    const float* qr = cb + (size_t)code0 * DD;
    bf16x8 a1f[3];
#pragma unroll
    for (int ks = 0; ks < 3; ++ks) {
        const int k0 = ks * 32 + quad * 8;
        bf16x8 v;
#pragma unroll
        for (int j = 0; j < 8; ++j) {
            float r = zr[k0 + j], q = qr[k0 + j];
            float d  = __fsub_rn(q, r);
            float st = __fadd_rn(r, d);
            v[j] = (short)f2bf(st);
        }
        a1f[ks] = v;
    }
    for (int nt = 0; nt < 12; ++nt) {
        const int n0 = nt * 16;
        f32x4 accv = {0.f, 0.f, 0.f, 0.f};
        const unsigned short* bw = (const unsigned short*)w1T + (n0 + col) * DD + quad * 8;
#pragma unroll
        for (int ks = 0; ks < 3; ++ks) {
            bf16x8 bf = *(const bf16x8*)(bw + ks * 32);
            accv = __builtin_amdgcn_mfma_f32_16x16x32_bf16(a1f[ks], bf, accv, 0, 0, 0);
        }
#pragma unroll
        for (int r = 0; r < 4; ++r) {
            float x = accv[r] + b1[n0 + col];
            float g = 0.5f * x * (1.0f + erff(x * 0.70710678118654752440f));
            hs[wv * 16 + quad * 4 + r][n0 + col] = f2bf(g);
        }
    }
    __syncthreads();
    bf16x8 a2f[6];
#pragma unroll
    for (int ks = 0; ks < 6; ++ks)
        a2f[ks] = *(const bf16x8*)(&hs[wv * 16 + col][ks * 32 + quad * 8]);
    double lsum = 0.0;
    for (int nt = 0; nt < 48; ++nt) {
        const int n0 = nt * 16;
        f32x4 accv = {0.f, 0.f, 0.f, 0.f};
        const unsigned short* bw = (const unsigned short*)w2T + (size_t)(n0 + col) * PROJ + quad * 8;
#pragma unroll
        for (int ks = 0; ks < 6; ++ks) {
            bf16x8 bf = *(const bf16x8*)(bw + ks * 32);
            accv = __builtin_amdgcn_mfma_f32_16x16x32_bf16(a2f[ks], bf, accv, 0, 0, 0);
        }
#pragma unroll
        for (int r = 0; r < 4; ++r) {
            float pred = accv[r] + b2[n0 + col];
            float dt = pred - tgt[(m0 + quad * 4 + r) * (long)W2V + n0 + col];
            lsum += (double)dt * (double)dt;
        }
    }
    for (int off = 32; off > 0; off >>= 1) lsum += __shfl_down(lsum, off, 64);
    if (lane == 0) atomicAdd(sem_acc, lsum);
}

// ---------------------------------------------------------------- finalize
__global__ void kf(const double* __restrict__ acc, float* __restrict__ dout) {
    if (threadIdx.x == 0 && blockIdx.x == 0) {
        float vq = 0.f;
        for (int s = 0; s < NCB; ++s) {
            float l = (float)(acc[s] / 12582912.0);   // mean over B*T*D
            vq = vq + l;          // embedding_loss
            vq = vq + 0.5f * l;   // COMMIT * commitment_loss (identical value)
        }
        dout[VQ_OFF]  = vq;
        dout[SEM_OFF] = (float)(acc[6] / 100663296.0); // mean over B*T*W2V
    }
}

extern "C" void kernel_launch(void* const* d_in, const int* in_sizes, int n_in,
                              void* d_out, int out_size, void* d_ws, size_t ws_size,
                              hipStream_t stream) {
    const float* z   = (const float*)d_in[0];
    const float* tgt = (const float*)d_in[1];
    const float* cb  = (const float*)d_in[2];
    const float* w1  = (const float*)d_in[3];
    const float* b1  = (const float*)d_in[4];
    const float* w2  = (const float*)d_in[5];
    const float* b2  = (const float*)d_in[6];
    float* out = (float*)d_out;
    char*  ws  = (char*)d_ws;

    double*          accs = (double*)(ws + ACC_OFF);
    float*           E32  = (float*)(ws + E32_OFF);
    __hip_bfloat16*  w1T  = (__hip_bfloat16*)(ws + W1T_OFF);
    __hip_bfloat16*  w2T  = (__hip_bfloat16*)(ws + W2T_OFF);

    kzero<<<dim3(1), dim3(64), 0, stream>>>(accs);
    kee  <<<dim3(9), dim3(256), 0, stream>>>(cb, E32);
    kwt  <<<dim3(648), dim3(256), 0, stream>>>(w1, w2, w1T, w2T);
    // kq2 uses the ZQT output region as residual scratch; kr overwrites after.
    kq2  <<<dim3(BT / TB), dim3(256), 0, stream>>>(z, cb, E32, out,
                                                   (float4*)(out + ZQT_OFF));
    kr   <<<dim3(512), dim3(256), 0, stream>>>(z, cb, out + CODES_OFF, out, accs);
    kh   <<<dim3(2048), dim3(256), 0, stream>>>(z, cb, out + CODES_OFF,
                                                w1T, b1, w2T, b2, tgt, accs + 6);
    kf   <<<dim3(1), dim3(64), 0, stream>>>(accs, out);
}